// Round 1
// baseline (7237.137 us; speedup 1.0000x reference)
//
#include <hip/hip_runtime.h>
#include <math.h>

#define Bn 64
#define Sn 64
#define Tn 20
#define TD 19
#define En 512
#define Hn 1024
#define Vn 32000
#define Kan 100
#define Lnn 50
#define Wnn 8

__device__ __forceinline__ float sigm(float x) { return 1.0f / (1.0f + expf(-x)); }

// ---------------------------------------------------------------------------
// Generic fp32 GEMM: C[M,N] = act(A @ W^T + b1 (+ b2))
// A: [M,K] row-major (lda); if GATHER, A row r is embed row tok[r].
// W: [N,*] row-major with row stride ldw.
// OUTMODE 0: C[r*ldc + n].  OUTMODE 1: logits scatter r=t*64+b -> out[(b*19+t)*V + n]
// K must be a multiple of 32.
// ---------------------------------------------------------------------------
template<int ACT, int OUTMODE, int GATHER>
__global__ __launch_bounds__(256)
void gemm_kernel(const float* __restrict__ A, int lda, const int* __restrict__ tok,
                 const float* __restrict__ W, int ldw,
                 const float* __restrict__ b1, const float* __restrict__ b2,
                 float* __restrict__ C, int ldc, int M, int N, int K)
{
    __shared__ __align__(16) float As[32][68];
    __shared__ __align__(16) float Ws[32][68];
    const int tx = threadIdx.x, ty = threadIdx.y;
    const int tid = ty * 16 + tx;
    const int n0 = blockIdx.x * 64;
    const int r0 = blockIdx.y * 64;
    float acc[4][4] = {};
    for (int k0 = 0; k0 < K; k0 += 32) {
#pragma unroll
        for (int p = 0; p < 8; ++p) {
            int idx = tid + p * 256;
            int row = idx >> 5, kk = idx & 31;
            int k = k0 + kk;
            int r = r0 + row;
            float av = 0.0f;
            if (r < M) {
                int ar = GATHER ? tok[r] : r;
                av = A[(size_t)ar * lda + k];
            }
            As[kk][row] = av;
            int n = n0 + row;
            float wv = 0.0f;
            if (n < N) wv = W[(size_t)n * ldw + k];
            Ws[kk][row] = wv;
        }
        __syncthreads();
#pragma unroll
        for (int kk = 0; kk < 32; ++kk) {
            const float4 a = *(const float4*)&As[kk][ty * 4];
            const float4 w = *(const float4*)&Ws[kk][tx * 4];
            acc[0][0] += a.x * w.x; acc[0][1] += a.x * w.y; acc[0][2] += a.x * w.z; acc[0][3] += a.x * w.w;
            acc[1][0] += a.y * w.x; acc[1][1] += a.y * w.y; acc[1][2] += a.y * w.z; acc[1][3] += a.y * w.w;
            acc[2][0] += a.z * w.x; acc[2][1] += a.z * w.y; acc[2][2] += a.z * w.z; acc[2][3] += a.z * w.w;
            acc[3][0] += a.w * w.x; acc[3][1] += a.w * w.y; acc[3][2] += a.w * w.z; acc[3][3] += a.w * w.w;
        }
        __syncthreads();
    }
#pragma unroll
    for (int i = 0; i < 4; ++i) {
        int r = r0 + ty * 4 + i;
        if (r >= M) continue;
#pragma unroll
        for (int j = 0; j < 4; ++j) {
            int n = n0 + tx * 4 + j;
            if (n >= N) continue;
            float v = acc[i][j];
            if (b1) v += b1[n];
            if (b2) v += b2[n];
            if (ACT == 1) v = tanhf(v);
            if (ACT == 2) v = fmaxf(v, 0.0f);
            if (OUTMODE == 0) {
                C[(size_t)r * ldc + n] = v;
            } else {
                int b = r & 63, t = r >> 6;
                C[(size_t)(b * TD + t) * Vn + n] = v;
            }
        }
    }
}

// ---------------------------------------------------------------------------
// Fused LSTM step: g = Xg + hprev@Whh^T (+ A2@W2^T), then gates -> hnext,cnext.
// Block (16,16): tx -> 16 h-indices (j0+tx), ty -> 16 batch rows (b0+ty).
// Each thread accumulates the 4 gate dots for its (b,j).
// Xg is [B, 4H] with biases already folded in.
// W2 (decoder) is dec_Wih + E with row stride ldw2 (ctx columns).
// ---------------------------------------------------------------------------
__global__ __launch_bounds__(256)
void lstm_step_kernel(const float* __restrict__ Xg,
                      const float* __restrict__ hprev,
                      const float* __restrict__ cprev,
                      const float* __restrict__ A2, int lda2,
                      const float* __restrict__ Whh,
                      const float* __restrict__ W2, int ldw2,
                      float* __restrict__ hnext, float* __restrict__ cnext,
                      float* __restrict__ hcopy,
                      const int* __restrict__ lengths, int t,
                      float* __restrict__ hlast, float* __restrict__ clast)
{
    __shared__ __align__(16) float hs2[32][17];
    __shared__ __align__(16) float Ws2[32][68];
    const int tx = threadIdx.x, ty = threadIdx.y;
    const int tid = ty * 16 + tx;
    const int j0 = blockIdx.x * 16;
    const int b0 = blockIdx.y * 16;
    float acc0 = 0.f, acc1 = 0.f, acc2 = 0.f, acc3 = 0.f;

    for (int k0 = 0; k0 < Hn; k0 += 32) {
#pragma unroll
        for (int p = 0; p < 2; ++p) {
            int idx = tid + p * 256;
            int rb = idx >> 5, kk = idx & 31;
            hs2[kk][rb] = hprev[(size_t)(b0 + rb) * Hn + k0 + kk];
        }
#pragma unroll
        for (int p = 0; p < 8; ++p) {
            int idx = tid + p * 256;
            int rw = idx >> 5, kk = idx & 31;
            int jj = rw >> 2, g = rw & 3;
            Ws2[kk][rw] = Whh[(size_t)(g * Hn + j0 + jj) * Hn + k0 + kk];
        }
        __syncthreads();
#pragma unroll
        for (int kk = 0; kk < 32; ++kk) {
            float hv = hs2[kk][ty];
            const float4 w = *(const float4*)&Ws2[kk][tx * 4];
            acc0 += hv * w.x; acc1 += hv * w.y; acc2 += hv * w.z; acc3 += hv * w.w;
        }
        __syncthreads();
    }
    if (A2) {
        for (int k0 = 0; k0 < Hn; k0 += 32) {
#pragma unroll
            for (int p = 0; p < 2; ++p) {
                int idx = tid + p * 256;
                int rb = idx >> 5, kk = idx & 31;
                hs2[kk][rb] = A2[(size_t)(b0 + rb) * lda2 + k0 + kk];
            }
#pragma unroll
            for (int p = 0; p < 8; ++p) {
                int idx = tid + p * 256;
                int rw = idx >> 5, kk = idx & 31;
                int jj = rw >> 2, g = rw & 3;
                Ws2[kk][rw] = W2[(size_t)(g * Hn + j0 + jj) * ldw2 + k0 + kk];
            }
            __syncthreads();
#pragma unroll
            for (int kk = 0; kk < 32; ++kk) {
                float hv = hs2[kk][ty];
                const float4 w = *(const float4*)&Ws2[kk][tx * 4];
                acc0 += hv * w.x; acc1 += hv * w.y; acc2 += hv * w.z; acc3 += hv * w.w;
            }
            __syncthreads();
        }
    }
    int b = b0 + ty, j = j0 + tx;
    const float* xg = Xg + (size_t)b * (4 * Hn);
    float gi = acc0 + xg[j];
    float gf = acc1 + xg[Hn + j];
    float gg = acc2 + xg[2 * Hn + j];
    float go = acc3 + xg[3 * Hn + j];
    float cn = sigm(gf) * cprev[(size_t)b * Hn + j] + sigm(gi) * tanhf(gg);
    float hn = sigm(go) * tanhf(cn);
    hnext[(size_t)b * Hn + j] = hn;
    cnext[(size_t)b * Hn + j] = cn;
    if (hcopy) hcopy[(size_t)b * 2048 + j] = hn;
    if (lengths && t == lengths[b] - 1) {
        hlast[(size_t)b * Hn + j] = hn;
        clast[(size_t)b * Hn + j] = cn;
    }
}

// ---------------------------------------------------------------------------
// Decoder attention for one step. One block per batch row b (256 thr, 4 waves).
// a_key = tanh(h[b] @ ak_W^T + ak_b); e = q_key[b] . a_key; softmax(masked);
// ctx = w @ q_value[b]. Writes ctx to ctx_out[b*2048 + j] (hcat ctx half).
// ---------------------------------------------------------------------------
__global__ __launch_bounds__(256)
void attn_kernel(const float* __restrict__ h,
                 const float* __restrict__ akW, const float* __restrict__ akb,
                 const float* __restrict__ qkey,
                 const float* __restrict__ qval,
                 const int* __restrict__ clen,
                 float* __restrict__ ctx_out)
{
    const int b = blockIdx.x;
    const int tid = threadIdx.x;
    const int lane = tid & 63, wv = tid >> 6;
    __shared__ float hsh[1024];
    __shared__ float akey[104];
    __shared__ float wts[52];

#pragma unroll
    for (int p = 0; p < 4; ++p) hsh[tid + p * 256] = h[(size_t)b * Hn + tid + p * 256];
    __syncthreads();

    // a_key: wave wv owns k = wv, wv+4, ...
    for (int k = wv; k < Kan; k += 4) {
        float s = 0.0f;
#pragma unroll
        for (int m = 0; m < 16; ++m)
            s += hsh[lane + m * 64] * akW[(size_t)k * Hn + lane + m * 64];
        for (int off = 32; off; off >>= 1) s += __shfl_down(s, off);
        if (lane == 0) akey[k] = tanhf(s + akb[k]);
    }
    __syncthreads();

    // e + masked softmax (wave 0)
    if (wv == 0) {
        float e;
        int len = clen[b];
        if (lane < Lnn) {
            if (lane < len) {
                float s = 0.0f;
                const float* qr = qkey + (size_t)(b * Lnn + lane) * Kan;
                for (int k = 0; k < Kan; ++k) s += qr[k] * akey[k];
                e = s;
            } else {
                e = -1e9f;
            }
        } else {
            e = -3.402823466e38f;
        }
        float mx = e;
        for (int off = 32; off; off >>= 1) mx = fmaxf(mx, __shfl_xor(mx, off));
        float p = (lane < Lnn) ? expf(e - mx) : 0.0f;
        float sm = p;
        for (int off = 32; off; off >>= 1) sm += __shfl_xor(sm, off);
        if (lane < Lnn) wts[lane] = p / sm;
    }
    __syncthreads();

    // ctx[j] = sum_l wts[l] * q_value[b,l,j]
#pragma unroll
    for (int p = 0; p < 4; ++p) {
        int j = tid + p * 256;
        float s = 0.0f;
        for (int l = 0; l < Lnn; ++l)
            s += wts[l] * qval[((size_t)b * Lnn + l) * Hn + j];
        ctx_out[(size_t)b * 2048 + j] = s;
    }
}

// ---------------------------------------------------------------------------
// ctx_embed[b,l,:] = mean over 8 words of embed rows. One block per (b,l).
// ---------------------------------------------------------------------------
__global__ __launch_bounds__(128)
void ctx_embed_kernel(const int* __restrict__ ctc, const float* __restrict__ embed,
                      float* __restrict__ ctxe)
{
    const int row = blockIdx.x;  // b*50 + l
    const int tid = threadIdx.x;
    __shared__ int toks[8];
    if (tid < 8) toks[tid] = ctc[row * Wnn + tid];
    __syncthreads();
#pragma unroll
    for (int p = 0; p < 4; ++p) {
        int e = tid + p * 128;
        float s = 0.0f;
#pragma unroll
        for (int w = 0; w < 8; ++w) s += embed[(size_t)toks[w] * En + e];
        ctxe[(size_t)row * En + e] = s * 0.125f;
    }
}

// token index prep for the gathered input-gate GEMMs (rows are r = t*B + b)
__global__ void prep_tokens(const int* __restrict__ src, const int* __restrict__ trg,
                            int* __restrict__ tokA, int* __restrict__ tokD)
{
    int i = blockIdx.x * 256 + threadIdx.x;
    if (i < Bn * Sn) tokA[i] = src[(i & 63) * Sn + (i >> 6)];
    if (i < TD * Bn) tokD[i] = trg[(i & 63) * Tn + (i >> 6)];
}

extern "C" void kernel_launch(void* const* d_in, const int* in_sizes, int n_in,
                              void* d_out, int out_size, void* d_ws, size_t ws_size,
                              hipStream_t stream)
{
    (void)in_sizes; (void)n_in; (void)out_size; (void)ws_size;
    const int*   src     = (const int*)d_in[0];
    const int*   srclen  = (const int*)d_in[1];
    const int*   trg     = (const int*)d_in[2];
    const int*   ctc     = (const int*)d_in[3];
    const int*   ctclen  = (const int*)d_in[4];
    const float* embed   = (const float*)d_in[5];
    const float* enc_Wih = (const float*)d_in[6];
    const float* enc_Whh = (const float*)d_in[7];
    const float* enc_bih = (const float*)d_in[8];
    const float* enc_bhh = (const float*)d_in[9];
    const float* dec_Wih = (const float*)d_in[10];
    const float* dec_Whh = (const float*)d_in[11];
    const float* dec_bih = (const float*)d_in[12];
    const float* dec_bhh = (const float*)d_in[13];
    const float* qkW     = (const float*)d_in[14];
    const float* qkb     = (const float*)d_in[15];
    const float* qvW     = (const float*)d_in[16];
    const float* qvb     = (const float*)d_in[17];
    const float* akW     = (const float*)d_in[18];
    const float* akb     = (const float*)d_in[19];
    const float* outW    = (const float*)d_in[20];
    const float* outb    = (const float*)d_in[21];
    const float* wdb     = (const float*)d_in[22];
    const float* hf1W    = (const float*)d_in[23];
    const float* hf1b    = (const float*)d_in[24];
    const float* hf2W    = (const float*)d_in[25];
    const float* hf2b    = (const float*)d_in[26];
    const float* cf1W    = (const float*)d_in[27];
    const float* cf1b    = (const float*)d_in[28];
    const float* cf2W    = (const float*)d_in[29];
    const float* cf2b    = (const float*)d_in[30];
    float* out = (float*)d_out;

    float* ws = (float*)d_ws;
    size_t off = 0;
    auto alloc = [&](size_t n) {
        float* p = ws + off;
        off += (n + 63) & ~(size_t)63;
        return p;
    };
    float* Xenc  = alloc((size_t)Sn * Bn * 4 * Hn);   // [S,B,4H] input gates (biases folded)
    float* Xdec  = alloc((size_t)TD * Bn * 4 * Hn);   // [T-1,B,4H]
    float* qkey  = alloc((size_t)Bn * Lnn * Kan);     // [B,L,K]
    float* qval  = alloc((size_t)Bn * Lnn * Hn);      // [B,L,H]
    float* ctxe  = alloc((size_t)Bn * Lnn * En);      // [B,L,E]
    float* hb0   = alloc((size_t)Bn * Hn);
    float* hb1   = alloc((size_t)Bn * Hn);
    float* cb0   = alloc((size_t)Bn * Hn);
    float* cb1   = alloc((size_t)Bn * Hn);
    float* hlast = alloc((size_t)Bn * Hn);
    float* clast = alloc((size_t)Bn * Hn);
    float* tmp2h = alloc((size_t)Bn * 2 * Hn);
    int*   tokA  = (int*)alloc(Bn * Sn);
    int*   tokD  = (int*)alloc(TD * Bn);
    // hcat/oxall alias the Xenc region: Xenc is dead once the encoder loop ends,
    // and hcat (1216*2048) + oxall (1216*512) fit well inside it.
    float* hcat  = Xenc;                               // [1216, 2048] = [h_t, ctx_t]
    float* oxall = Xenc + (size_t)TD * Bn * 2048;      // [1216, 512]

    dim3 blk(16, 16);

    prep_tokens<<<16, 256, 0, stream>>>(src, trg, tokA, tokD);
    ctx_embed_kernel<<<Bn * Lnn, 128, 0, stream>>>(ctc, embed, ctxe);

    // Encoder input gates: [4096,512] x [512,4096] + bih + bhh
    gemm_kernel<0, 0, 1><<<dim3(64, 64), blk, 0, stream>>>(
        embed, En, tokA, enc_Wih, En, enc_bih, enc_bhh, Xenc, 4 * Hn, Bn * Sn, 4 * Hn, En);
    // Decoder input gates (x-part of dec_Wih): [1216,512] x [512,4096] + biases
    gemm_kernel<0, 0, 1><<<dim3(64, TD), blk, 0, stream>>>(
        embed, En, tokD, dec_Wih, En + Hn, dec_bih, dec_bhh, Xdec, 4 * Hn, TD * Bn, 4 * Hn, En);
    // q_key = tanh(ctxe @ qk_W^T + qk_b)
    gemm_kernel<1, 0, 0><<<dim3(2, 50), blk, 0, stream>>>(
        ctxe, En, nullptr, qkW, En, qkb, nullptr, qkey, Kan, Bn * Lnn, Kan, En);
    // q_value = ctxe @ qv_W^T + qv_b
    gemm_kernel<0, 0, 0><<<dim3(16, 50), blk, 0, stream>>>(
        ctxe, En, nullptr, qvW, En, qvb, nullptr, qval, Hn, Bn * Lnn, Hn, En);

    hipMemsetAsync(hb0, 0, (size_t)Bn * Hn * sizeof(float), stream);
    hipMemsetAsync(cb0, 0, (size_t)Bn * Hn * sizeof(float), stream);

    float* hb[2] = {hb0, hb1};
    float* cb[2] = {cb0, cb1};

    // ---- encoder recurrence ----
    for (int t = 0; t < Sn; ++t) {
        lstm_step_kernel<<<dim3(64, 4), blk, 0, stream>>>(
            Xenc + (size_t)t * Bn * 4 * Hn, hb[t & 1], cb[t & 1],
            nullptr, 0, enc_Whh, nullptr, 0,
            hb[(t + 1) & 1], cb[(t + 1) & 1], nullptr,
            srclen, t, hlast, clast);
    }

    // ---- init_hidden MLPs: h0 -> hb0, c0 -> cb0 ----
    gemm_kernel<2, 0, 0><<<dim3(32, 1), blk, 0, stream>>>(
        hlast, Hn, nullptr, hf1W, Hn, hf1b, nullptr, tmp2h, 2 * Hn, Bn, 2 * Hn, Hn);
    gemm_kernel<0, 0, 0><<<dim3(16, 1), blk, 0, stream>>>(
        tmp2h, 2 * Hn, nullptr, hf2W, 2 * Hn, hf2b, nullptr, hb0, Hn, Bn, Hn, 2 * Hn);
    gemm_kernel<2, 0, 0><<<dim3(32, 1), blk, 0, stream>>>(
        clast, Hn, nullptr, cf1W, Hn, cf1b, nullptr, tmp2h, 2 * Hn, Bn, 2 * Hn, Hn);
    gemm_kernel<0, 0, 0><<<dim3(16, 1), blk, 0, stream>>>(
        tmp2h, 2 * Hn, nullptr, cf2W, 2 * Hn, cf2b, nullptr, cb0, Hn, Bn, Hn, 2 * Hn);

    // ---- decoder recurrence ----
    for (int t = 0; t < TD; ++t) {
        float* hcat_t = hcat + (size_t)t * Bn * 2048;
        attn_kernel<<<Bn, 256, 0, stream>>>(
            hb[t & 1], akW, akb, qkey, qval, ctclen, hcat_t + Hn);
        lstm_step_kernel<<<dim3(64, 4), blk, 0, stream>>>(
            Xdec + (size_t)t * Bn * 4 * Hn, hb[t & 1], cb[t & 1],
            hcat_t + Hn, 2048, dec_Whh, dec_Wih + En, En + Hn,
            hb[(t + 1) & 1], cb[(t + 1) & 1], hcat_t,
            nullptr, 0, nullptr, nullptr);
    }

    // ---- batched epilogue: ox then logits ----
    gemm_kernel<0, 0, 0><<<dim3(8, TD), blk, 0, stream>>>(
        hcat, 2048, nullptr, outW, 2 * Hn, outb, nullptr, oxall, En, TD * Bn, En, 2 * Hn);
    gemm_kernel<0, 1, 0><<<dim3(Vn / 64, TD), blk, 0, stream>>>(
        oxall, En, nullptr, embed, En, wdb, nullptr, out, 0, TD * Bn, Vn, En);
}

// Round 2
// 4094.767 us; speedup vs baseline: 1.7674x; 1.7674x over previous
//
#include <hip/hip_runtime.h>
#include <hip/hip_bf16.h>
#include <math.h>

#define Bn 64
#define Sn 64
#define Tn 20
#define TD 19
#define En 512
#define Hn 1024
#define Vn 32000
#define Kan 100
#define Lnn 50
#define Wnn 8

typedef __attribute__((ext_vector_type(8))) short short8v;
typedef __attribute__((ext_vector_type(4))) float floatx4;
typedef __hip_bfloat16 bf16;

__device__ __forceinline__ float sigm(float x) { return 1.0f / (1.0f + expf(-x)); }

// XOR-swizzled LDS element offset for a [rows][32] bf16 tile staged in 16B slots.
// p = 16B-slot index (0..3). Keeps ds_read_b128 fragment reads ~2-way (free).
#define EOFF(r, p) (((r) << 5) + ((((p) ^ ((r) & 3))) << 3))

// ===========================================================================
// bf16 MFMA GEMM: C[M,N] = A @ W^T (+ b1 (+ b2)), 128x128 tile, BK=32.
// A: bf16 [M][lda] (row gathered via tok if GATHER). W: bf16 [N][ldw].
// EPI 0: optional fp32 C store + optional bf16 Cbf store.
// EPI 2: logits scatter r=t*64+b -> C[(b*19+t)*V + n]  (C fp32, bias b1).
// Requires: N % 128 == 0, K % 32 == 0. M guarded.
// ===========================================================================
template<int GATHER, int EPI>
__global__ __launch_bounds__(256)
void mgemm(const bf16* __restrict__ A, int lda, const int* __restrict__ tok,
           const bf16* __restrict__ W, int ldw,
           const float* __restrict__ b1, const float* __restrict__ b2,
           float* __restrict__ C, int ldc,
           bf16* __restrict__ Cbf, int ldcbf,
           int M, int N, int K)
{
    __shared__ bf16 As[128 * 32];
    __shared__ bf16 Bs[128 * 32];
    const int tid = threadIdx.x;
    const int lane = tid & 63, wv = tid >> 6;
    const int wm = wv >> 1, wn = wv & 1;
    const int r0 = blockIdx.y * 128, n0 = blockIdx.x * 128;
    const int srow = tid >> 2, sp = tid & 3;

    const int ra_r0 = r0 + srow, ra_r1 = r0 + srow + 64;
    const bool av0 = ra_r0 < M, av1 = ra_r1 < M;
    const size_t arow0 = (size_t)(av0 ? (GATHER ? tok[ra_r0] : ra_r0) : 0) * lda;
    const size_t arow1 = (size_t)(av1 ? (GATHER ? tok[ra_r1] : ra_r1) : 0) * lda;
    const size_t wrow0 = (size_t)(n0 + srow) * ldw;
    const size_t wrow1 = (size_t)(n0 + srow + 64) * ldw;

    const uint4 z4 = make_uint4(0, 0, 0, 0);
    uint4 ra0, ra1, rb0, rb1;
#define LOADTILE_G(k0) do { \
        ra0 = av0 ? *((const uint4*)(A + arow0 + (k0)) + sp) : z4; \
        ra1 = av1 ? *((const uint4*)(A + arow1 + (k0)) + sp) : z4; \
        rb0 = *((const uint4*)(W + wrow0 + (k0)) + sp); \
        rb1 = *((const uint4*)(W + wrow1 + (k0)) + sp); \
    } while (0)

    floatx4 acc[4][4] = {};
    const int lr = lane & 15, p2 = lane >> 4;

    LOADTILE_G(0);
    for (int k0 = 0; k0 < K; k0 += 32) {
        __syncthreads();
        *(uint4*)(As + EOFF(srow, sp)) = ra0;
        *(uint4*)(As + EOFF(srow + 64, sp)) = ra1;
        *(uint4*)(Bs + EOFF(srow, sp)) = rb0;
        *(uint4*)(Bs + EOFF(srow + 64, sp)) = rb1;
        __syncthreads();
        if (k0 + 32 < K) LOADTILE_G(k0 + 32);
        short8v aF[4], bF[4];
#pragma unroll
        for (int mf = 0; mf < 4; ++mf)
            aF[mf] = *(const short8v*)(As + EOFF(wm * 64 + mf * 16 + lr, p2));
#pragma unroll
        for (int nf = 0; nf < 4; ++nf)
            bF[nf] = *(const short8v*)(Bs + EOFF(wn * 64 + nf * 16 + lr, p2));
#pragma unroll
        for (int mf = 0; mf < 4; ++mf)
#pragma unroll
            for (int nf = 0; nf < 4; ++nf)
                acc[mf][nf] = __builtin_amdgcn_mfma_f32_16x16x32_bf16(
                    aF[mf], bF[nf], acc[mf][nf], 0, 0, 0);
    }
#undef LOADTILE_G

    const int rbase = r0 + wm * 64 + (lane >> 4) * 4;
    const int nbase = n0 + wn * 64 + (lane & 15);
#pragma unroll
    for (int nf = 0; nf < 4; ++nf) {
        const int n = nbase + nf * 16;
        float bias = b1 ? b1[n] : 0.0f;
        if (b2) bias += b2[n];
#pragma unroll
        for (int mf = 0; mf < 4; ++mf) {
#pragma unroll
            for (int i = 0; i < 4; ++i) {
                const int r = rbase + mf * 16 + i;
                if (r >= M) continue;
                float v = acc[mf][nf][i] + bias;
                if (EPI == 2) {
                    int b = r & 63, t = r >> 6;
                    C[(size_t)(b * TD + t) * Vn + n] = v;
                } else {
                    if (C) C[(size_t)r * ldc + n] = v;
                    if (Cbf) Cbf[(size_t)r * ldcbf + n] = __float2bfloat16(v);
                }
            }
        }
    }
}

// ===========================================================================
// Fused MFMA LSTM step. BM=64 (full batch), BN=128 (= 32 j's x 4 gates with
// gate-permuted weights Wp[(j*4+g)][k]). grid = 32 blocks, 256 threads.
// acc = Ah @ Wp^T ; gates finished with Xg (bf16, original g*H+j layout),
// then c/h update + exports.
// ===========================================================================
__global__ __launch_bounds__(256)
void lstm_mfma(const bf16* __restrict__ Ah, int lda,
               const bf16* __restrict__ Wp,
               const bf16* __restrict__ Xg,
               const float* __restrict__ cprev, float* __restrict__ cnext,
               float* __restrict__ hfp,
               bf16* __restrict__ hbf, int ldhbf,
               bf16* __restrict__ hbf2,
               const int* __restrict__ lengths, int t,
               float* __restrict__ hlast, float* __restrict__ clast,
               int K)
{
    __shared__ bf16 As[64 * 32];
    __shared__ bf16 Bs[128 * 32];
    __shared__ float Gs[64][133];
    const int tid = threadIdx.x;
    const int lane = tid & 63, wn = tid >> 6;
    const int n0 = blockIdx.x * 128;
    const int srow = tid >> 2, sp = tid & 3;

    const size_t arow = (size_t)srow * lda;
    const size_t wrow0 = (size_t)(n0 + srow) * K;
    const size_t wrow1 = (size_t)(n0 + srow + 64) * K;

    uint4 ra0, rb0, rb1;
#define LOADTILE_L(k0) do { \
        ra0 = *((const uint4*)(Ah + arow + (k0)) + sp); \
        rb0 = *((const uint4*)(Wp + wrow0 + (k0)) + sp); \
        rb1 = *((const uint4*)(Wp + wrow1 + (k0)) + sp); \
    } while (0)

    floatx4 acc[4][2] = {};
    const int lr = lane & 15, p2 = lane >> 4;

    LOADTILE_L(0);
    for (int k0 = 0; k0 < K; k0 += 32) {
        __syncthreads();
        *(uint4*)(As + EOFF(srow, sp)) = ra0;
        *(uint4*)(Bs + EOFF(srow, sp)) = rb0;
        *(uint4*)(Bs + EOFF(srow + 64, sp)) = rb1;
        __syncthreads();
        if (k0 + 32 < K) LOADTILE_L(k0 + 32);
        short8v aF[4], bF[2];
#pragma unroll
        for (int mf = 0; mf < 4; ++mf)
            aF[mf] = *(const short8v*)(As + EOFF(mf * 16 + lr, p2));
#pragma unroll
        for (int nf = 0; nf < 2; ++nf)
            bF[nf] = *(const short8v*)(Bs + EOFF(wn * 32 + nf * 16 + lr, p2));
#pragma unroll
        for (int mf = 0; mf < 4; ++mf)
#pragma unroll
            for (int nf = 0; nf < 2; ++nf)
                acc[mf][nf] = __builtin_amdgcn_mfma_f32_16x16x32_bf16(
                    aF[mf], bF[nf], acc[mf][nf], 0, 0, 0);
    }
#undef LOADTILE_L

    // scatter accumulators into the per-block gate buffer
#pragma unroll
    for (int mf = 0; mf < 4; ++mf)
#pragma unroll
        for (int nf = 0; nf < 2; ++nf)
#pragma unroll
            for (int i = 0; i < 4; ++i)
                Gs[(lane >> 4) * 4 + i + mf * 16][wn * 32 + nf * 16 + (lane & 15)] =
                    acc[mf][nf][i];
    __syncthreads();

    // finish: 2048 (b, jl) cells / 256 threads = 8 each
#pragma unroll
    for (int it = 0; it < 8; ++it) {
        int cell = tid + it * 256;
        int jl = cell & 31, b = cell >> 5;
        int j = (n0 >> 2) + jl;
        const bf16* xg = Xg + (size_t)b * 4096;
        float gi = Gs[b][jl * 4 + 0] + __bfloat162float(xg[j]);
        float gf = Gs[b][jl * 4 + 1] + __bfloat162float(xg[1024 + j]);
        float gg = Gs[b][jl * 4 + 2] + __bfloat162float(xg[2048 + j]);
        float go = Gs[b][jl * 4 + 3] + __bfloat162float(xg[3072 + j]);
        float cp = cprev[b * 1024 + j];
        float cnv = sigm(gf) * cp + sigm(gi) * tanhf(gg);
        float hnv = sigm(go) * tanhf(cnv);
        cnext[b * 1024 + j] = cnv;
        hbf[(size_t)b * ldhbf + j] = __float2bfloat16(hnv);
        if (hfp) hfp[b * 1024 + j] = hnv;
        if (hbf2) hbf2[(size_t)b * 2048 + j] = __float2bfloat16(hnv);
        if (lengths && t == lengths[b] - 1) {
            hlast[b * 1024 + j] = hnv;
            clast[b * 1024 + j] = cnv;
        }
    }
}

// ===========================================================================
// fp32 fallback GEMM (small shapes: q_key N=100, init MLPs M=64)
// ===========================================================================
template<int ACT>
__global__ __launch_bounds__(256)
void gemm_kernel(const float* __restrict__ A, int lda,
                 const float* __restrict__ W, int ldw,
                 const float* __restrict__ b1,
                 float* __restrict__ C, int ldc, int M, int N, int K)
{
    __shared__ __align__(16) float As[32][68];
    __shared__ __align__(16) float Ws[32][68];
    const int tx = threadIdx.x, ty = threadIdx.y;
    const int tid = ty * 16 + tx;
    const int n0 = blockIdx.x * 64;
    const int r0 = blockIdx.y * 64;
    float acc[4][4] = {};
    for (int k0 = 0; k0 < K; k0 += 32) {
#pragma unroll
        for (int p = 0; p < 8; ++p) {
            int idx = tid + p * 256;
            int row = idx >> 5, kk = idx & 31;
            int k = k0 + kk;
            int r = r0 + row;
            As[kk][row] = (r < M) ? A[(size_t)r * lda + k] : 0.0f;
            int n = n0 + row;
            Ws[kk][row] = (n < N) ? W[(size_t)n * ldw + k] : 0.0f;
        }
        __syncthreads();
#pragma unroll
        for (int kk = 0; kk < 32; ++kk) {
            const float4 a = *(const float4*)&As[kk][ty * 4];
            const float4 w = *(const float4*)&Ws[kk][tx * 4];
            acc[0][0] += a.x * w.x; acc[0][1] += a.x * w.y; acc[0][2] += a.x * w.z; acc[0][3] += a.x * w.w;
            acc[1][0] += a.y * w.x; acc[1][1] += a.y * w.y; acc[1][2] += a.y * w.z; acc[1][3] += a.y * w.w;
            acc[2][0] += a.z * w.x; acc[2][1] += a.z * w.y; acc[2][2] += a.z * w.z; acc[2][3] += a.z * w.w;
            acc[3][0] += a.w * w.x; acc[3][1] += a.w * w.y; acc[3][2] += a.w * w.z; acc[3][3] += a.w * w.w;
        }
        __syncthreads();
    }
#pragma unroll
    for (int i = 0; i < 4; ++i) {
        int r = r0 + ty * 4 + i;
        if (r >= M) continue;
#pragma unroll
        for (int j = 0; j < 4; ++j) {
            int n = n0 + tx * 4 + j;
            if (n >= N) continue;
            float v = acc[i][j] + b1[n];
            if (ACT == 1) v = tanhf(v);
            if (ACT == 2) v = fmaxf(v, 0.0f);
            C[(size_t)r * ldc + n] = v;
        }
    }
}

// ===========================================================================
// Decoder attention (fp32). Writes ctx as bf16 to two strided destinations.
// ===========================================================================
__global__ __launch_bounds__(256)
void attn_kernel(const float* __restrict__ h,
                 const float* __restrict__ akW, const float* __restrict__ akb,
                 const float* __restrict__ qkey,
                 const float* __restrict__ qval,
                 const int* __restrict__ clen,
                 bf16* __restrict__ ctx1,   // a2 buffer ctx half, stride 2048
                 bf16* __restrict__ ctx2)   // hcat_bf ctx half, stride 2048
{
    const int b = blockIdx.x;
    const int tid = threadIdx.x;
    const int lane = tid & 63, wv = tid >> 6;
    __shared__ float hsh[1024];
    __shared__ float akey[104];
    __shared__ float wts[52];

#pragma unroll
    for (int p = 0; p < 4; ++p) hsh[tid + p * 256] = h[(size_t)b * Hn + tid + p * 256];
    __syncthreads();

    for (int k = wv; k < Kan; k += 4) {
        float s = 0.0f;
#pragma unroll
        for (int m = 0; m < 16; ++m)
            s += hsh[lane + m * 64] * akW[(size_t)k * Hn + lane + m * 64];
        for (int off = 32; off; off >>= 1) s += __shfl_down(s, off);
        if (lane == 0) akey[k] = tanhf(s + akb[k]);
    }
    __syncthreads();

    if (wv == 0) {
        float e;
        int len = clen[b];
        if (lane < Lnn) {
            if (lane < len) {
                float s = 0.0f;
                const float* qr = qkey + (size_t)(b * Lnn + lane) * Kan;
                for (int k = 0; k < Kan; ++k) s += qr[k] * akey[k];
                e = s;
            } else {
                e = -1e9f;
            }
        } else {
            e = -3.402823466e38f;
        }
        float mx = e;
        for (int off = 32; off; off >>= 1) mx = fmaxf(mx, __shfl_xor(mx, off));
        float p = (lane < Lnn) ? expf(e - mx) : 0.0f;
        float sm = p;
        for (int off = 32; off; off >>= 1) sm += __shfl_xor(sm, off);
        if (lane < Lnn) wts[lane] = p / sm;
    }
    __syncthreads();

#pragma unroll
    for (int p = 0; p < 4; ++p) {
        int j = tid + p * 256;
        float s = 0.0f;
        for (int l = 0; l < Lnn; ++l)
            s += wts[l] * qval[((size_t)b * Lnn + l) * Hn + j];
        bf16 v = __float2bfloat16(s);
        ctx1[(size_t)b * 2048 + j] = v;
        ctx2[(size_t)b * 2048 + j] = v;
    }
}

// ---------------------------------------------------------------------------
__global__ __launch_bounds__(128)
void ctx_embed_kernel(const int* __restrict__ ctc, const float* __restrict__ embed,
                      float* __restrict__ ctxe, bf16* __restrict__ ctxe_bf)
{
    const int row = blockIdx.x;  // b*50 + l
    const int tid = threadIdx.x;
    __shared__ int toks[8];
    if (tid < 8) toks[tid] = ctc[row * Wnn + tid];
    __syncthreads();
#pragma unroll
    for (int p = 0; p < 4; ++p) {
        int e = tid + p * 128;
        float s = 0.0f;
#pragma unroll
        for (int w = 0; w < 8; ++w) s += embed[(size_t)toks[w] * En + e];
        s *= 0.125f;
        ctxe[(size_t)row * En + e] = s;
        ctxe_bf[(size_t)row * En + e] = __float2bfloat16(s);
    }
}

__global__ void prep_tokens(const int* __restrict__ src, const int* __restrict__ trg,
                            int* __restrict__ tokA, int* __restrict__ tokD)
{
    int i = blockIdx.x * 256 + threadIdx.x;
    if (i < Bn * Sn) tokA[i] = src[(i & 63) * Sn + (i >> 6)];
    if (i < TD * Bn) tokD[i] = trg[(i & 63) * Tn + (i >> 6)];
}

__global__ void conv_f2b(const float* __restrict__ src, bf16* __restrict__ dst, int n)
{
    int i = (blockIdx.x * 256 + threadIdx.x) * 4;
    if (i >= n) return;
    float4 v = *(const float4*)(src + i);
    dst[i + 0] = __float2bfloat16(v.x);
    dst[i + 1] = __float2bfloat16(v.y);
    dst[i + 2] = __float2bfloat16(v.z);
    dst[i + 3] = __float2bfloat16(v.w);
}

// gate-permute encoder Whh: Wp[(j*4+g)][k] = Whh[(g*1024+j)][k]
__global__ void perm_enc(const float* __restrict__ Whh, bf16* __restrict__ Wp)
{
    int row = blockIdx.x;
    int j = row >> 2, g = row & 3;
    const float* s = Whh + (size_t)(g * 1024 + j) * 1024;
    bf16* d = Wp + (size_t)row * 1024;
    for (int e = threadIdx.x; e < 1024; e += 256) d[e] = __float2bfloat16(s[e]);
}

// gate-permute decoder [Whh | Wih_ctx]: Wp[(j*4+g)][0:1024]=Whh, [1024:2048]=Wih[:,512:]
__global__ void perm_dec(const float* __restrict__ Whh, const float* __restrict__ Wih,
                         bf16* __restrict__ Wp)
{
    int row = blockIdx.x;
    int j = row >> 2, g = row & 3;
    int sr = g * 1024 + j;
    const float* s1 = Whh + (size_t)sr * 1024;
    const float* s2 = Wih + (size_t)sr * 1536 + 512;
    bf16* d = Wp + (size_t)row * 2048;
    for (int e = threadIdx.x; e < 1024; e += 256) {
        d[e] = __float2bfloat16(s1[e]);
        d[1024 + e] = __float2bfloat16(s2[e]);
    }
}

// h0 fp32 [64][1024] -> bf16 into a2 buffer h-half (stride 2048)
__global__ void conv_h0(const float* __restrict__ src, bf16* __restrict__ dst)
{
    int i = blockIdx.x * 256 + threadIdx.x;
    int b = i >> 10, j = i & 1023;
    dst[(size_t)b * 2048 + j] = __float2bfloat16(src[i]);
}

extern "C" void kernel_launch(void* const* d_in, const int* in_sizes, int n_in,
                              void* d_out, int out_size, void* d_ws, size_t ws_size,
                              hipStream_t stream)
{
    (void)in_sizes; (void)n_in; (void)out_size; (void)ws_size;
    const int*   src     = (const int*)d_in[0];
    const int*   srclen  = (const int*)d_in[1];
    const int*   trg     = (const int*)d_in[2];
    const int*   ctc     = (const int*)d_in[3];
    const int*   ctclen  = (const int*)d_in[4];
    const float* embed   = (const float*)d_in[5];
    const float* enc_Wih = (const float*)d_in[6];
    const float* enc_Whh = (const float*)d_in[7];
    const float* enc_bih = (const float*)d_in[8];
    const float* enc_bhh = (const float*)d_in[9];
    const float* dec_Wih = (const float*)d_in[10];
    const float* dec_Whh = (const float*)d_in[11];
    const float* dec_bih = (const float*)d_in[12];
    const float* dec_bhh = (const float*)d_in[13];
    const float* qkW     = (const float*)d_in[14];
    const float* qkb     = (const float*)d_in[15];
    const float* qvW     = (const float*)d_in[16];
    const float* qvb     = (const float*)d_in[17];
    const float* akW     = (const float*)d_in[18];
    const float* akb     = (const float*)d_in[19];
    const float* outW    = (const float*)d_in[20];
    const float* outb    = (const float*)d_in[21];
    const float* wdb     = (const float*)d_in[22];
    const float* hf1W    = (const float*)d_in[23];
    const float* hf1b    = (const float*)d_in[24];
    const float* hf2W    = (const float*)d_in[25];
    const float* hf2b    = (const float*)d_in[26];
    const float* cf1W    = (const float*)d_in[27];
    const float* cf1b    = (const float*)d_in[28];
    const float* cf2W    = (const float*)d_in[29];
    const float* cf2b    = (const float*)d_in[30];
    float* out = (float*)d_out;

    char* ws = (char*)d_ws;
    size_t off = 0;
    auto alloc = [&](size_t bytes) -> void* {
        void* p = ws + off;
        off += (bytes + 255) & ~(size_t)255;
        return p;
    };
    bf16*  embed_bf  = (bf16*)alloc((size_t)Vn * En * 2);
    bf16*  encWih_bf = (bf16*)alloc((size_t)4096 * En * 2);
    bf16*  decWih_bf = (bf16*)alloc((size_t)4096 * 1536 * 2);
    bf16*  qvW_bf    = (bf16*)alloc((size_t)Hn * En * 2);
    bf16*  outW_bf   = (bf16*)alloc((size_t)En * 2048 * 2);
    bf16*  Wenc_p    = (bf16*)alloc((size_t)4096 * 1024 * 2);
    bf16*  Wdec_p    = (bf16*)alloc((size_t)4096 * 2048 * 2);
    bf16*  Xenc_bf   = (bf16*)alloc((size_t)Sn * Bn * 4096 * 2);
    bf16*  Xdec_bf   = (bf16*)alloc((size_t)TD * Bn * 4096 * 2);
    float* qkey      = (float*)alloc((size_t)Bn * Lnn * Kan * 4);
    float* qval      = (float*)alloc((size_t)Bn * Lnn * Hn * 4);
    float* ctxe      = (float*)alloc((size_t)Bn * Lnn * En * 4);
    bf16*  ctxe_bf   = (bf16*)alloc((size_t)Bn * Lnn * En * 2);
    bf16*  a2e0      = (bf16*)alloc((size_t)Bn * 1024 * 2);
    bf16*  a2e1      = (bf16*)alloc((size_t)Bn * 1024 * 2);
    bf16*  a2d0      = (bf16*)alloc((size_t)Bn * 2048 * 2);
    bf16*  a2d1      = (bf16*)alloc((size_t)Bn * 2048 * 2);
    float* cbuf0     = (float*)alloc((size_t)Bn * Hn * 4);
    float* cbuf1     = (float*)alloc((size_t)Bn * Hn * 4);
    float* hbd0      = (float*)alloc((size_t)Bn * Hn * 4);
    float* hbd1      = (float*)alloc((size_t)Bn * Hn * 4);
    float* hlast     = (float*)alloc((size_t)Bn * Hn * 4);
    float* clast     = (float*)alloc((size_t)Bn * Hn * 4);
    float* tmp2h     = (float*)alloc((size_t)Bn * 2 * Hn * 4);
    int*   tokA      = (int*)alloc((size_t)Bn * Sn * 4);
    int*   tokD      = (int*)alloc((size_t)TD * Bn * 4);
    // hcat_bf / ox_bf alias Xenc_bf (dead after the encoder loop)
    bf16*  hcat_bf   = Xenc_bf;                              // [1216][2048]
    bf16*  ox_bf     = Xenc_bf + (size_t)TD * Bn * 2048;     // [1216][512]

    // ---- weight / embedding conversions ----
    conv_f2b<<<(Vn * En) / 1024, 256, 0, stream>>>(embed, embed_bf, Vn * En);
    conv_f2b<<<(4096 * En) / 1024, 256, 0, stream>>>(enc_Wih, encWih_bf, 4096 * En);
    conv_f2b<<<(4096 * 1536) / 1024, 256, 0, stream>>>(dec_Wih, decWih_bf, 4096 * 1536);
    conv_f2b<<<(Hn * En) / 1024, 256, 0, stream>>>(qvW, qvW_bf, Hn * En);
    conv_f2b<<<(En * 2048) / 1024, 256, 0, stream>>>(outW, outW_bf, En * 2048);
    perm_enc<<<4096, 256, 0, stream>>>(enc_Whh, Wenc_p);
    perm_dec<<<4096, 256, 0, stream>>>(dec_Whh, dec_Wih, Wdec_p);
    prep_tokens<<<16, 256, 0, stream>>>(src, trg, tokA, tokD);
    ctx_embed_kernel<<<Bn * Lnn, 128, 0, stream>>>(ctc, embed, ctxe, ctxe_bf);

    // ---- batched input-gate GEMMs + q projections ----
    mgemm<1, 0><<<dim3(32, 32), 256, 0, stream>>>(
        embed_bf, En, tokA, encWih_bf, En, enc_bih, enc_bhh,
        nullptr, 0, Xenc_bf, 4096, Bn * Sn, 4096, En);
    mgemm<1, 0><<<dim3(32, 10), 256, 0, stream>>>(
        embed_bf, En, tokD, decWih_bf, 1536, dec_bih, dec_bhh,
        nullptr, 0, Xdec_bf, 4096, TD * Bn, 4096, En);
    mgemm<0, 0><<<dim3(8, 25), 256, 0, stream>>>(
        ctxe_bf, En, nullptr, qvW_bf, En, qvb, nullptr,
        qval, Hn, nullptr, 0, Bn * Lnn, Hn, En);
    gemm_kernel<1><<<dim3(2, 50), dim3(16, 16), 0, stream>>>(
        ctxe, En, qkW, En, qkb, qkey, Kan, Bn * Lnn, Kan, En);

    hipMemsetAsync(a2e0, 0, (size_t)Bn * 1024 * 2, stream);
    hipMemsetAsync(cbuf0, 0, (size_t)Bn * Hn * 4, stream);

    bf16*  a2e[2] = {a2e0, a2e1};
    bf16*  a2d[2] = {a2d0, a2d1};
    float* cb[2]  = {cbuf0, cbuf1};
    float* hbd[2] = {hbd0, hbd1};

    // ---- encoder recurrence (64 fused MFMA steps) ----
    for (int t = 0; t < Sn; ++t) {
        lstm_mfma<<<32, 256, 0, stream>>>(
            a2e[t & 1], 1024, Wenc_p, Xenc_bf + (size_t)t * Bn * 4096,
            cb[t & 1], cb[(t + 1) & 1],
            nullptr, a2e[(t + 1) & 1], 1024, nullptr,
            srclen, t, hlast, clast, 1024);
    }

    // ---- init_hidden MLPs (fp32, tiny) ----
    gemm_kernel<2><<<dim3(32, 1), dim3(16, 16), 0, stream>>>(
        hlast, Hn, hf1W, Hn, hf1b, tmp2h, 2 * Hn, Bn, 2 * Hn, Hn);
    gemm_kernel<0><<<dim3(16, 1), dim3(16, 16), 0, stream>>>(
        tmp2h, 2 * Hn, hf2W, 2 * Hn, hf2b, hbd0, Hn, Bn, Hn, 2 * Hn);
    gemm_kernel<2><<<dim3(32, 1), dim3(16, 16), 0, stream>>>(
        clast, Hn, cf1W, Hn, cf1b, tmp2h, 2 * Hn, Bn, 2 * Hn, Hn);
    gemm_kernel<0><<<dim3(16, 1), dim3(16, 16), 0, stream>>>(
        tmp2h, 2 * Hn, cf2W, 2 * Hn, cf2b, cbuf0, Hn, Bn, Hn, 2 * Hn);
    conv_h0<<<256, 256, 0, stream>>>(hbd0, a2d0);

    // ---- decoder recurrence ----
    for (int t = 0; t < TD; ++t) {
        bf16* hcat_t = hcat_bf + (size_t)t * Bn * 2048;
        attn_kernel<<<Bn, 256, 0, stream>>>(
            hbd[t & 1], akW, akb, qkey, qval, ctclen,
            a2d[t & 1] + 1024, hcat_t + 1024);
        lstm_mfma<<<32, 256, 0, stream>>>(
            a2d[t & 1], 2048, Wdec_p, Xdec_bf + (size_t)t * Bn * 4096,
            cb[t & 1], cb[(t + 1) & 1],
            hbd[(t + 1) & 1], a2d[(t + 1) & 1], 2048, hcat_t,
            nullptr, 0, nullptr, nullptr, 2048);
    }

    // ---- batched epilogue: ox then logits ----
    mgemm<0, 0><<<dim3(4, 10), 256, 0, stream>>>(
        hcat_bf, 2048, nullptr, outW_bf, 2048, outb, nullptr,
        nullptr, 0, ox_bf, En, TD * Bn, En, 2048);
    mgemm<0, 2><<<dim3(Vn / 128, 10), 256, 0, stream>>>(
        ox_bf, En, nullptr, embed_bf, En, wdb, nullptr,
        out, 0, nullptr, 0, TD * Bn, Vn, En);
}

// Round 3
// 2902.907 us; speedup vs baseline: 2.4931x; 1.4106x over previous
//
#include <hip/hip_runtime.h>
#include <hip/hip_bf16.h>
#include <math.h>

#define Bn 64
#define Sn 64
#define Tn 20
#define TD 19
#define En 512
#define Hn 1024
#define Vn 32000
#define Kan 100
#define Lnn 50
#define Wnn 8

typedef __attribute__((ext_vector_type(8))) short short8v;
typedef __attribute__((ext_vector_type(4))) float floatx4;
typedef __hip_bfloat16 bf16;

__device__ __forceinline__ float sigm(float x) { return 1.0f / (1.0f + expf(-x)); }

// XOR-swizzled LDS element offset for a [rows][32] bf16 tile staged in 16B slots.
#define EOFF(r, p) (((r) << 5) + ((((p) ^ ((r) & 3))) << 3))

// ===========================================================================
// bf16 MFMA GEMM: C[M,N] = act(A @ W^T + b1 (+ b2)), 128x128 tile, BK=32.
// A: bf16 [M][lda] (row gathered via tok if GATHER). W: bf16 [N][ldw].
// EPI 0: optional fp32 C store + optional bf16 Cbf store (both guarded n<N).
// EPI 2: logits scatter r=t*64+b -> C[(b*19+t)*V + n].
// ACT 0: none, 1: tanh, 2: relu.
// Requires: W valid for ceil128(N) rows (pad if needed), K % 32 == 0.
// ===========================================================================
template<int GATHER, int EPI, int ACT>
__global__ __launch_bounds__(256)
void mgemm(const bf16* __restrict__ A, int lda, const int* __restrict__ tok,
           const bf16* __restrict__ W, int ldw,
           const float* __restrict__ b1, const float* __restrict__ b2,
           float* __restrict__ C, int ldc,
           bf16* __restrict__ Cbf, int ldcbf,
           int M, int N, int K)
{
    __shared__ bf16 As[128 * 32];
    __shared__ bf16 Bs[128 * 32];
    const int tid = threadIdx.x;
    const int lane = tid & 63, wv = tid >> 6;
    const int wm = wv >> 1, wn = wv & 1;
    const int r0 = blockIdx.y * 128, n0 = blockIdx.x * 128;
    const int srow = tid >> 2, sp = tid & 3;

    const int ra_r0 = r0 + srow, ra_r1 = r0 + srow + 64;
    const bool av0 = ra_r0 < M, av1 = ra_r1 < M;
    const size_t arow0 = (size_t)(av0 ? (GATHER ? tok[ra_r0] : ra_r0) : 0) * lda;
    const size_t arow1 = (size_t)(av1 ? (GATHER ? tok[ra_r1] : ra_r1) : 0) * lda;
    const size_t wrow0 = (size_t)(n0 + srow) * ldw;
    const size_t wrow1 = (size_t)(n0 + srow + 64) * ldw;

    const uint4 z4 = make_uint4(0, 0, 0, 0);
    uint4 ra0, ra1, rb0, rb1;
#define LOADTILE_G(k0) do { \
        ra0 = av0 ? *((const uint4*)(A + arow0 + (k0)) + sp) : z4; \
        ra1 = av1 ? *((const uint4*)(A + arow1 + (k0)) + sp) : z4; \
        rb0 = *((const uint4*)(W + wrow0 + (k0)) + sp); \
        rb1 = *((const uint4*)(W + wrow1 + (k0)) + sp); \
    } while (0)

    floatx4 acc[4][4] = {};
    const int lr = lane & 15, p2 = lane >> 4;

    LOADTILE_G(0);
    for (int k0 = 0; k0 < K; k0 += 32) {
        __syncthreads();
        *(uint4*)(As + EOFF(srow, sp)) = ra0;
        *(uint4*)(As + EOFF(srow + 64, sp)) = ra1;
        *(uint4*)(Bs + EOFF(srow, sp)) = rb0;
        *(uint4*)(Bs + EOFF(srow + 64, sp)) = rb1;
        __syncthreads();
        if (k0 + 32 < K) LOADTILE_G(k0 + 32);
        short8v aF[4], bF[4];
#pragma unroll
        for (int mf = 0; mf < 4; ++mf)
            aF[mf] = *(const short8v*)(As + EOFF(wm * 64 + mf * 16 + lr, p2));
#pragma unroll
        for (int nf = 0; nf < 4; ++nf)
            bF[nf] = *(const short8v*)(Bs + EOFF(wn * 64 + nf * 16 + lr, p2));
#pragma unroll
        for (int mf = 0; mf < 4; ++mf)
#pragma unroll
            for (int nf = 0; nf < 4; ++nf)
                acc[mf][nf] = __builtin_amdgcn_mfma_f32_16x16x32_bf16(
                    aF[mf], bF[nf], acc[mf][nf], 0, 0, 0);
    }
#undef LOADTILE_G

    const int rbase = r0 + wm * 64 + (lane >> 4) * 4;
    const int nbase = n0 + wn * 64 + (lane & 15);
#pragma unroll
    for (int nf = 0; nf < 4; ++nf) {
        const int n = nbase + nf * 16;
        if (n >= N) continue;
        float bias = b1 ? b1[n] : 0.0f;
        if (b2) bias += b2[n];
#pragma unroll
        for (int mf = 0; mf < 4; ++mf) {
#pragma unroll
            for (int i = 0; i < 4; ++i) {
                const int r = rbase + mf * 16 + i;
                if (r >= M) continue;
                float v = acc[mf][nf][i] + bias;
                if (ACT == 1) v = tanhf(v);
                if (ACT == 2) v = fmaxf(v, 0.0f);
                if (EPI == 2) {
                    int b = r & 63, t = r >> 6;
                    C[(size_t)(b * TD + t) * Vn + n] = v;
                } else {
                    if (C) C[(size_t)r * ldc + n] = v;
                    if (Cbf) Cbf[(size_t)r * ldcbf + n] = __float2bfloat16(v);
                }
            }
        }
    }
}

// ===========================================================================
// Fused MFMA LSTM step. BM=64 (full batch), BN=128 (= 32 j's x 4 gates with
// gate-permuted weights Wp[(j*4+g)][k]). grid = 32 blocks, 256 threads.
// ===========================================================================
__global__ __launch_bounds__(256)
void lstm_mfma(const bf16* __restrict__ Ah, int lda,
               const bf16* __restrict__ Wp,
               const bf16* __restrict__ Xg,
               const float* __restrict__ cprev, float* __restrict__ cnext,
               float* __restrict__ hfp,
               bf16* __restrict__ hbf, int ldhbf,
               bf16* __restrict__ hbf2,
               const int* __restrict__ lengths, int t,
               float* __restrict__ hlast, float* __restrict__ clast,
               int K)
{
    __shared__ bf16 As[64 * 32];
    __shared__ bf16 Bs[128 * 32];
    __shared__ float Gs[64][133];
    const int tid = threadIdx.x;
    const int lane = tid & 63, wn = tid >> 6;
    const int n0 = blockIdx.x * 128;
    const int srow = tid >> 2, sp = tid & 3;

    const size_t arow = (size_t)srow * lda;
    const size_t wrow0 = (size_t)(n0 + srow) * K;
    const size_t wrow1 = (size_t)(n0 + srow + 64) * K;

    uint4 ra0, rb0, rb1;
#define LOADTILE_L(k0) do { \
        ra0 = *((const uint4*)(Ah + arow + (k0)) + sp); \
        rb0 = *((const uint4*)(Wp + wrow0 + (k0)) + sp); \
        rb1 = *((const uint4*)(Wp + wrow1 + (k0)) + sp); \
    } while (0)

    floatx4 acc[4][2] = {};
    const int lr = lane & 15, p2 = lane >> 4;

    LOADTILE_L(0);
    for (int k0 = 0; k0 < K; k0 += 32) {
        __syncthreads();
        *(uint4*)(As + EOFF(srow, sp)) = ra0;
        *(uint4*)(Bs + EOFF(srow, sp)) = rb0;
        *(uint4*)(Bs + EOFF(srow + 64, sp)) = rb1;
        __syncthreads();
        if (k0 + 32 < K) LOADTILE_L(k0 + 32);
        short8v aF[4], bF[2];
#pragma unroll
        for (int mf = 0; mf < 4; ++mf)
            aF[mf] = *(const short8v*)(As + EOFF(mf * 16 + lr, p2));
#pragma unroll
        for (int nf = 0; nf < 2; ++nf)
            bF[nf] = *(const short8v*)(Bs + EOFF(wn * 32 + nf * 16 + lr, p2));
#pragma unroll
        for (int mf = 0; mf < 4; ++mf)
#pragma unroll
            for (int nf = 0; nf < 2; ++nf)
                acc[mf][nf] = __builtin_amdgcn_mfma_f32_16x16x32_bf16(
                    aF[mf], bF[nf], acc[mf][nf], 0, 0, 0);
    }
#undef LOADTILE_L

#pragma unroll
    for (int mf = 0; mf < 4; ++mf)
#pragma unroll
        for (int nf = 0; nf < 2; ++nf)
#pragma unroll
            for (int i = 0; i < 4; ++i)
                Gs[(lane >> 4) * 4 + i + mf * 16][wn * 32 + nf * 16 + (lane & 15)] =
                    acc[mf][nf][i];
    __syncthreads();

#pragma unroll
    for (int it = 0; it < 8; ++it) {
        int cell = tid + it * 256;
        int jl = cell & 31, b = cell >> 5;
        int j = (n0 >> 2) + jl;
        const bf16* xg = Xg + (size_t)b * 4096;
        float gi = Gs[b][jl * 4 + 0] + __bfloat162float(xg[j]);
        float gf = Gs[b][jl * 4 + 1] + __bfloat162float(xg[1024 + j]);
        float gg = Gs[b][jl * 4 + 2] + __bfloat162float(xg[2048 + j]);
        float go = Gs[b][jl * 4 + 3] + __bfloat162float(xg[3072 + j]);
        float cp = cprev[b * 1024 + j];
        float cnv = sigm(gf) * cp + sigm(gi) * tanhf(gg);
        float hnv = sigm(go) * tanhf(cnv);
        cnext[b * 1024 + j] = cnv;
        hbf[(size_t)b * ldhbf + j] = __float2bfloat16(hnv);
        if (hfp) hfp[b * 1024 + j] = hnv;
        if (hbf2) hbf2[(size_t)b * 2048 + j] = __float2bfloat16(hnv);
        if (lengths && t == lengths[b] - 1) {
            hlast[b * 1024 + j] = hnv;
            clast[b * 1024 + j] = cnv;
        }
    }
}

// ===========================================================================
// Decoder attention (fp32). Writes ctx as bf16 to two strided destinations.
// ===========================================================================
__global__ __launch_bounds__(256)
void attn_kernel(const float* __restrict__ h,
                 const float* __restrict__ akW, const float* __restrict__ akb,
                 const float* __restrict__ qkey,
                 const float* __restrict__ qval,
                 const int* __restrict__ clen,
                 bf16* __restrict__ ctx1,
                 bf16* __restrict__ ctx2)
{
    const int b = blockIdx.x;
    const int tid = threadIdx.x;
    const int lane = tid & 63, wv = tid >> 6;
    __shared__ float hsh[1024];
    __shared__ float akey[104];
    __shared__ float wts[52];

#pragma unroll
    for (int p = 0; p < 4; ++p) hsh[tid + p * 256] = h[(size_t)b * Hn + tid + p * 256];
    __syncthreads();

    for (int k = wv; k < Kan; k += 4) {
        float s = 0.0f;
#pragma unroll
        for (int m = 0; m < 16; ++m)
            s += hsh[lane + m * 64] * akW[(size_t)k * Hn + lane + m * 64];
        for (int off = 32; off; off >>= 1) s += __shfl_down(s, off);
        if (lane == 0) akey[k] = tanhf(s + akb[k]);
    }
    __syncthreads();

    if (wv == 0) {
        float e;
        int len = clen[b];
        if (lane < Lnn) {
            if (lane < len) {
                float s = 0.0f;
                const float* qr = qkey + (size_t)(b * Lnn + lane) * Kan;
                for (int k = 0; k < Kan; ++k) s += qr[k] * akey[k];
                e = s;
            } else {
                e = -1e9f;
            }
        } else {
            e = -3.402823466e38f;
        }
        float mx = e;
        for (int off = 32; off; off >>= 1) mx = fmaxf(mx, __shfl_xor(mx, off));
        float p = (lane < Lnn) ? expf(e - mx) : 0.0f;
        float sm = p;
        for (int off = 32; off; off >>= 1) sm += __shfl_xor(sm, off);
        if (lane < Lnn) wts[lane] = p / sm;
    }
    __syncthreads();

#pragma unroll
    for (int p = 0; p < 4; ++p) {
        int j = tid + p * 256;
        float s = 0.0f;
        for (int l = 0; l < Lnn; ++l)
            s += wts[l] * qval[((size_t)b * Lnn + l) * Hn + j];
        bf16 v = __float2bfloat16(s);
        ctx1[(size_t)b * 2048 + j] = v;
        ctx2[(size_t)b * 2048 + j] = v;
    }
}

// ---------------------------------------------------------------------------
__global__ __launch_bounds__(128)
void ctx_embed_kernel(const int* __restrict__ ctc, const float* __restrict__ embed,
                      bf16* __restrict__ ctxe_bf)
{
    const int row = blockIdx.x;  // b*50 + l
    const int tid = threadIdx.x;
    __shared__ int toks[8];
    if (tid < 8) toks[tid] = ctc[row * Wnn + tid];
    __syncthreads();
#pragma unroll
    for (int p = 0; p < 4; ++p) {
        int e = tid + p * 128;
        float s = 0.0f;
#pragma unroll
        for (int w = 0; w < 8; ++w) s += embed[(size_t)toks[w] * En + e];
        ctxe_bf[(size_t)row * En + e] = __float2bfloat16(s * 0.125f);
    }
}

__global__ void prep_tokens(const int* __restrict__ src, const int* __restrict__ trg,
                            int* __restrict__ tokA, int* __restrict__ tokD)
{
    int i = blockIdx.x * 256 + threadIdx.x;
    if (i < Bn * Sn) tokA[i] = src[(i & 63) * Sn + (i >> 6)];
    if (i < TD * Bn) tokD[i] = trg[(i & 63) * Tn + (i >> 6)];
}

__global__ void conv_f2b(const float* __restrict__ src, bf16* __restrict__ dst, int n)
{
    int i = (blockIdx.x * 256 + threadIdx.x) * 4;
    if (i >= n) return;
    float4 v = *(const float4*)(src + i);
    dst[i + 0] = __float2bfloat16(v.x);
    dst[i + 1] = __float2bfloat16(v.y);
    dst[i + 2] = __float2bfloat16(v.z);
    dst[i + 3] = __float2bfloat16(v.w);
}

// pad qk_W [100][512] -> bf16 [128][512] (zero rows 100..127)
__global__ void pad_qkw(const float* __restrict__ qkW, bf16* __restrict__ Wp)
{
    int i = blockIdx.x * 256 + threadIdx.x;  // 128*512
    int r = i >> 9;
    Wp[i] = __float2bfloat16(r < Kan ? qkW[(size_t)r * En + (i & 511)] : 0.0f);
}

// gate-permute encoder Whh: Wp[(j*4+g)][k] = Whh[(g*1024+j)][k]
__global__ void perm_enc(const float* __restrict__ Whh, bf16* __restrict__ Wp)
{
    int row = blockIdx.x;
    int j = row >> 2, g = row & 3;
    const float* s = Whh + (size_t)(g * 1024 + j) * 1024;
    bf16* d = Wp + (size_t)row * 1024;
    for (int e = threadIdx.x; e < 1024; e += 256) d[e] = __float2bfloat16(s[e]);
}

// gate-permute decoder [Whh | Wih_ctx]
__global__ void perm_dec(const float* __restrict__ Whh, const float* __restrict__ Wih,
                         bf16* __restrict__ Wp)
{
    int row = blockIdx.x;
    int j = row >> 2, g = row & 3;
    int sr = g * 1024 + j;
    const float* s1 = Whh + (size_t)sr * 1024;
    const float* s2 = Wih + (size_t)sr * 1536 + 512;
    bf16* d = Wp + (size_t)row * 2048;
    for (int e = threadIdx.x; e < 1024; e += 256) {
        d[e] = __float2bfloat16(s1[e]);
        d[1024 + e] = __float2bfloat16(s2[e]);
    }
}

extern "C" void kernel_launch(void* const* d_in, const int* in_sizes, int n_in,
                              void* d_out, int out_size, void* d_ws, size_t ws_size,
                              hipStream_t stream)
{
    (void)in_sizes; (void)n_in; (void)out_size; (void)ws_size;
    const int*   src     = (const int*)d_in[0];
    const int*   srclen  = (const int*)d_in[1];
    const int*   trg     = (const int*)d_in[2];
    const int*   ctc     = (const int*)d_in[3];
    const int*   ctclen  = (const int*)d_in[4];
    const float* embed   = (const float*)d_in[5];
    const float* enc_Wih = (const float*)d_in[6];
    const float* enc_Whh = (const float*)d_in[7];
    const float* enc_bih = (const float*)d_in[8];
    const float* enc_bhh = (const float*)d_in[9];
    const float* dec_Wih = (const float*)d_in[10];
    const float* dec_Whh = (const float*)d_in[11];
    const float* dec_bih = (const float*)d_in[12];
    const float* dec_bhh = (const float*)d_in[13];
    const float* qkW     = (const float*)d_in[14];
    const float* qkb     = (const float*)d_in[15];
    const float* qvW     = (const float*)d_in[16];
    const float* qvb     = (const float*)d_in[17];
    const float* akW     = (const float*)d_in[18];
    const float* akb     = (const float*)d_in[19];
    const float* outW    = (const float*)d_in[20];
    const float* outb    = (const float*)d_in[21];
    const float* wdb     = (const float*)d_in[22];
    const float* hf1W    = (const float*)d_in[23];
    const float* hf1b    = (const float*)d_in[24];
    const float* hf2W    = (const float*)d_in[25];
    const float* hf2b    = (const float*)d_in[26];
    const float* cf1W    = (const float*)d_in[27];
    const float* cf1b    = (const float*)d_in[28];
    const float* cf2W    = (const float*)d_in[29];
    const float* cf2b    = (const float*)d_in[30];
    float* out = (float*)d_out;

    char* ws = (char*)d_ws;
    size_t off = 0;
    auto alloc = [&](size_t bytes) -> void* {
        void* p = ws + off;
        off += (bytes + 255) & ~(size_t)255;
        return p;
    };
    bf16*  embed_bf  = (bf16*)alloc((size_t)Vn * En * 2);
    bf16*  encWih_bf = (bf16*)alloc((size_t)4096 * En * 2);
    bf16*  decWih_bf = (bf16*)alloc((size_t)4096 * 1536 * 2);
    bf16*  qvW_bf    = (bf16*)alloc((size_t)Hn * En * 2);
    bf16*  outW_bf   = (bf16*)alloc((size_t)En * 2048 * 2);
    bf16*  Wenc_p    = (bf16*)alloc((size_t)4096 * 1024 * 2);
    bf16*  Wdec_p    = (bf16*)alloc((size_t)4096 * 2048 * 2);
    bf16*  hf1W_bf   = (bf16*)alloc((size_t)2048 * 1024 * 2);
    bf16*  hf2W_bf   = (bf16*)alloc((size_t)1024 * 2048 * 2);
    bf16*  cf1W_bf   = (bf16*)alloc((size_t)2048 * 1024 * 2);
    bf16*  cf2W_bf   = (bf16*)alloc((size_t)1024 * 2048 * 2);
    bf16*  qkWp      = (bf16*)alloc((size_t)128 * En * 2);
    bf16*  Xenc_bf   = (bf16*)alloc((size_t)Sn * Bn * 4096 * 2);
    bf16*  Xdec_bf   = (bf16*)alloc((size_t)TD * Bn * 4096 * 2);
    float* qkey      = (float*)alloc((size_t)Bn * Lnn * Kan * 4);
    float* qval      = (float*)alloc((size_t)Bn * Lnn * Hn * 4);
    bf16*  ctxe_bf   = (bf16*)alloc((size_t)Bn * Lnn * En * 2);
    bf16*  a2e0      = (bf16*)alloc((size_t)Bn * 1024 * 2);
    bf16*  a2e1      = (bf16*)alloc((size_t)Bn * 1024 * 2);
    bf16*  a2d0      = (bf16*)alloc((size_t)Bn * 2048 * 2);
    bf16*  a2d1      = (bf16*)alloc((size_t)Bn * 2048 * 2);
    float* cbuf0     = (float*)alloc((size_t)Bn * Hn * 4);
    float* cbuf1     = (float*)alloc((size_t)Bn * Hn * 4);
    float* hbd0      = (float*)alloc((size_t)Bn * Hn * 4);
    float* hbd1      = (float*)alloc((size_t)Bn * Hn * 4);
    float* hlast     = (float*)alloc((size_t)Bn * Hn * 4);
    float* clast     = (float*)alloc((size_t)Bn * Hn * 4);
    bf16*  hlast_bf  = (bf16*)alloc((size_t)Bn * Hn * 2);
    bf16*  clast_bf  = (bf16*)alloc((size_t)Bn * Hn * 2);
    bf16*  t2h_bf    = (bf16*)alloc((size_t)Bn * 2048 * 2);
    bf16*  t2c_bf    = (bf16*)alloc((size_t)Bn * 2048 * 2);
    int*   tokA      = (int*)alloc((size_t)Bn * Sn * 4);
    int*   tokD      = (int*)alloc((size_t)TD * Bn * 4);
    // hcat_bf / ox_bf alias Xenc_bf (dead after the encoder loop)
    bf16*  hcat_bf   = Xenc_bf;                              // [1216][2048]
    bf16*  ox_bf     = Xenc_bf + (size_t)TD * Bn * 2048;     // [1216][512]

    // ---- weight / embedding conversions ----
    conv_f2b<<<(Vn * En) / 1024, 256, 0, stream>>>(embed, embed_bf, Vn * En);
    conv_f2b<<<(4096 * En) / 1024, 256, 0, stream>>>(enc_Wih, encWih_bf, 4096 * En);
    conv_f2b<<<(4096 * 1536) / 1024, 256, 0, stream>>>(dec_Wih, decWih_bf, 4096 * 1536);
    conv_f2b<<<(Hn * En) / 1024, 256, 0, stream>>>(qvW, qvW_bf, Hn * En);
    conv_f2b<<<(En * 2048) / 1024, 256, 0, stream>>>(outW, outW_bf, En * 2048);
    conv_f2b<<<(2048 * 1024) / 1024, 256, 0, stream>>>(hf1W, hf1W_bf, 2048 * 1024);
    conv_f2b<<<(1024 * 2048) / 1024, 256, 0, stream>>>(hf2W, hf2W_bf, 1024 * 2048);
    conv_f2b<<<(2048 * 1024) / 1024, 256, 0, stream>>>(cf1W, cf1W_bf, 2048 * 1024);
    conv_f2b<<<(1024 * 2048) / 1024, 256, 0, stream>>>(cf2W, cf2W_bf, 1024 * 2048);
    pad_qkw<<<(128 * En) / 256, 256, 0, stream>>>(qkW, qkWp);
    perm_enc<<<4096, 256, 0, stream>>>(enc_Whh, Wenc_p);
    perm_dec<<<4096, 256, 0, stream>>>(dec_Whh, dec_Wih, Wdec_p);
    prep_tokens<<<16, 256, 0, stream>>>(src, trg, tokA, tokD);
    ctx_embed_kernel<<<Bn * Lnn, 128, 0, stream>>>(ctc, embed, ctxe_bf);

    // ---- batched input-gate GEMMs + q projections ----
    mgemm<1, 0, 0><<<dim3(32, 32), 256, 0, stream>>>(
        embed_bf, En, tokA, encWih_bf, En, enc_bih, enc_bhh,
        nullptr, 0, Xenc_bf, 4096, Bn * Sn, 4096, En);
    mgemm<1, 0, 0><<<dim3(32, 10), 256, 0, stream>>>(
        embed_bf, En, tokD, decWih_bf, 1536, dec_bih, dec_bhh,
        nullptr, 0, Xdec_bf, 4096, TD * Bn, 4096, En);
    mgemm<0, 0, 0><<<dim3(8, 25), 256, 0, stream>>>(
        ctxe_bf, En, nullptr, qvW_bf, En, qvb, nullptr,
        qval, Hn, nullptr, 0, Bn * Lnn, Hn, En);
    mgemm<0, 0, 1><<<dim3(1, 25), 256, 0, stream>>>(
        ctxe_bf, En, nullptr, qkWp, En, qkb, nullptr,
        qkey, Kan, nullptr, 0, Bn * Lnn, Kan, En);

    hipMemsetAsync(a2e0, 0, (size_t)Bn * 1024 * 2, stream);
    hipMemsetAsync(cbuf0, 0, (size_t)Bn * Hn * 4, stream);

    bf16*  a2e[2] = {a2e0, a2e1};
    bf16*  a2d[2] = {a2d0, a2d1};
    float* cb[2]  = {cbuf0, cbuf1};
    float* hbd[2] = {hbd0, hbd1};

    // ---- encoder recurrence (64 fused MFMA steps) ----
    for (int t = 0; t < Sn; ++t) {
        lstm_mfma<<<32, 256, 0, stream>>>(
            a2e[t & 1], 1024, Wenc_p, Xenc_bf + (size_t)t * Bn * 4096,
            cb[t & 1], cb[(t + 1) & 1],
            nullptr, a2e[(t + 1) & 1], 1024, nullptr,
            srclen, t, hlast, clast, 1024);
    }

    // ---- init_hidden MLPs (now MFMA) ----
    conv_f2b<<<(Bn * Hn) / 1024, 256, 0, stream>>>(hlast, hlast_bf, Bn * Hn);
    conv_f2b<<<(Bn * Hn) / 1024, 256, 0, stream>>>(clast, clast_bf, Bn * Hn);
    mgemm<0, 0, 2><<<dim3(16, 1), 256, 0, stream>>>(
        hlast_bf, Hn, nullptr, hf1W_bf, Hn, hf1b, nullptr,
        nullptr, 0, t2h_bf, 2048, Bn, 2048, Hn);
    mgemm<0, 0, 0><<<dim3(8, 1), 256, 0, stream>>>(
        t2h_bf, 2048, nullptr, hf2W_bf, 2048, hf2b, nullptr,
        hbd0, Hn, a2d0, 2048, Bn, Hn, 2048);
    mgemm<0, 0, 2><<<dim3(16, 1), 256, 0, stream>>>(
        clast_bf, Hn, nullptr, cf1W_bf, Hn, cf1b, nullptr,
        nullptr, 0, t2c_bf, 2048, Bn, 2048, Hn);
    mgemm<0, 0, 0><<<dim3(8, 1), 256, 0, stream>>>(
        t2c_bf, 2048, nullptr, cf2W_bf, 2048, cf2b, nullptr,
        cbuf0, Hn, nullptr, 0, Bn, Hn, 2048);

    // ---- decoder recurrence ----
    for (int t = 0; t < TD; ++t) {
        bf16* hcat_t = hcat_bf + (size_t)t * Bn * 2048;
        attn_kernel<<<Bn, 256, 0, stream>>>(
            hbd[t & 1], akW, akb, qkey, qval, ctclen,
            a2d[t & 1] + 1024, hcat_t + 1024);
        lstm_mfma<<<32, 256, 0, stream>>>(
            a2d[t & 1], 2048, Wdec_p, Xdec_bf + (size_t)t * Bn * 4096,
            cb[t & 1], cb[(t + 1) & 1],
            hbd[(t + 1) & 1], a2d[(t + 1) & 1], 2048, hcat_t,
            nullptr, 0, nullptr, nullptr, 2048);
    }

    // ---- batched epilogue: ox then logits ----
    mgemm<0, 0, 0><<<dim3(4, 10), 256, 0, stream>>>(
        hcat_bf, 2048, nullptr, outW_bf, 2048, outb, nullptr,
        nullptr, 0, ox_bf, En, TD * Bn, En, 2048);
    mgemm<0, 2, 0><<<dim3(Vn / 128, 10), 256, 0, stream>>>(
        ox_bf, En, nullptr, embed_bf, En, wdb, nullptr,
        out, 0, nullptr, 0, TD * Bn, Vn, En);
}